// Round 2
// baseline (1608.671 us; speedup 1.0000x reference)
//
#include <hip/hip_runtime.h>
#include <hip/hip_fp16.h>

#define N_NODES 10000
#define N_EDGES 60000
#define EPAD    60032   // multiple of 128

typedef _Float16 f16;
typedef f16 f16x8 __attribute__((ext_vector_type(8)));
typedef float f32x4 __attribute__((ext_vector_type(4)));

// ---------------- node encoder: h = relu(x@nW1+nb1)@nW2+nb2 ----------------
__global__ void k_node_enc(const float* __restrict__ x, const float* __restrict__ W1,
                           const float* __restrict__ b1, const float* __restrict__ W2,
                           const float* __restrict__ b2, float* __restrict__ h) {
    __shared__ float t[4][64];
    int g = threadIdx.x >> 6, j = threadIdx.x & 63;
    int node = blockIdx.x * 4 + g;
    float acc = b1[j];
#pragma unroll
    for (int i = 0; i < 6; ++i) acc += x[node * 6 + i] * W1[i * 64 + j];
    t[g][j] = fmaxf(acc, 0.f);
    __syncthreads();
    float acc2 = b2[j];
#pragma unroll
    for (int i = 0; i < 64; ++i) acc2 += t[g][i] * W2[i * 64 + j];
    h[node * 64 + j] = acc2;
}

// ---------------- condition encoder -----------------------------------------
__global__ void k_cond_enc(const float* __restrict__ cond, const float* __restrict__ scl,
                           const float* __restrict__ W1, const float* __restrict__ b1,
                           const float* __restrict__ W2, const float* __restrict__ b2,
                           float* __restrict__ u, float* __restrict__ out_u) {
    __shared__ float t[4][64];
    __shared__ float cat[4][14];
    int g = threadIdx.x >> 6, j = threadIdx.x & 63;
    if (threadIdx.x < 56) {
        int b = threadIdx.x / 14, i = threadIdx.x % 14;
        cat[b][i] = (i < 10) ? cond[b * 10 + i] : scl[b * 4 + (i - 10)];
    }
    __syncthreads();
    float acc = b1[j];
#pragma unroll
    for (int i = 0; i < 14; ++i) acc += cat[g][i] * W1[i * 64 + j];
    t[g][j] = fmaxf(acc, 0.f);
    __syncthreads();
    float acc2 = b2[j];
#pragma unroll
    for (int i = 0; i < 64; ++i) acc2 += t[g][i] * W2[i * 64 + j];
    u[g * 64 + j] = acc2;
    out_u[g * 64 + j] = acc2;
}

// ---------------- degree -----------------------------------------------------
__global__ void k_deg(const int* __restrict__ dst, float* __restrict__ deg) {
    int e = blockIdx.x * 256 + threadIdx.x;
    if (e < N_EDGES) atomicAdd(&deg[dst[e]], 1.0f);
}
__global__ void k_deg_inv(float* __restrict__ deg) {
    int n = blockIdx.x * 256 + threadIdx.x;
    if (n < N_NODES) deg[n] = 1.0f / fmaxf(deg[n], 1.0f);
}

// ------- permute kW3: kW3P[o*64+i][k] = kW3[k][i*64+o], fp16  ----------------
__global__ void k_permute(const float* __restrict__ kW3, f16* __restrict__ kW3P) {
    __shared__ float T[256][65];
    int i = blockIdx.x;                 // 0..63
    int o = threadIdx.x & 63, kq = threadIdx.x >> 6;
    for (int kk = 0; kk < 64; ++kk) {
        int k = kk * 4 + kq;
        T[k][o] = kW3[(size_t)k * 4096 + i * 64 + o];
    }
    __syncthreads();
    int ow = threadIdx.x >> 2, kc = (threadIdx.x & 3) * 64;
    f16* dstp = kW3P + (size_t)(ow * 64 + i) * 256 + kc;
    for (int c = 0; c < 8; ++c) {
        f16x8 v;
#pragma unroll
        for (int jj = 0; jj < 8; ++jj) v[jj] = (f16)T[kc + c * 8 + jj][ow];
        *(f16x8*)(dstp + c * 8) = v;
    }
}

// ---------------- fused edge MLP (k1 in LDS, k2 fp16 out) --------------------
__global__ __launch_bounds__(256) void k_edge12(const float* __restrict__ ea, const int* __restrict__ ei,
                                                const int* __restrict__ batch, const float* __restrict__ u,
                                                const float* __restrict__ W1, const float* __restrict__ b1,
                                                const float* __restrict__ W2, const float* __restrict__ b2,
                                                f16* __restrict__ k2) {
    __shared__ float u_s[256];
    __shared__ float ea_s[16][6];
    __shared__ int b_s[16];
    __shared__ float k1_s[16][128];
    int tid = threadIdx.x;
    int e0 = blockIdx.x * 16;
    u_s[tid] = u[tid];
    if (tid < 96) {
        int e = tid / 6, i = tid % 6;
        int eg = e0 + e;
        ea_s[e][i] = (eg < N_EDGES) ? ea[(size_t)eg * 6 + i] : 0.f;
    }
    if (tid < 16) {
        int eg = e0 + tid;
        b_s[tid] = (eg < N_EDGES) ? batch[ei[eg]] : 0;
    }
    __syncthreads();
    int j = tid & 127;
#pragma unroll 1
    for (int p = 0; p < 8; ++p) {
        int e = p * 2 + (tid >> 7);
        float acc = b1[j];
#pragma unroll
        for (int i = 0; i < 6; ++i) acc += ea_s[e][i] * W1[i * 128 + j];
        const float* ur = u_s + b_s[e] * 64;
#pragma unroll
        for (int i = 0; i < 64; ++i) acc += ur[i] * W1[(6 + i) * 128 + j];
        k1_s[e][j] = fmaxf(acc, 0.f);
    }
    __syncthreads();
    float acc2[16];
#pragma unroll
    for (int e = 0; e < 16; ++e) acc2[e] = b2[tid];
    for (int i = 0; i < 128; ++i) {
        float w = W2[(size_t)i * 256 + tid];
#pragma unroll
        for (int e = 0; e < 16; ++e) acc2[e] += k1_s[e][i] * w;
    }
#pragma unroll
    for (int e = 0; e < 16; ++e) {
        int eg = e0 + e;
        k2[(size_t)eg * 256 + tid] = (f16)((eg < N_EDGES) ? fmaxf(acc2[e], 0.f) : 0.f);
    }
}

// ---------------- hb[n][o] = sum_i h[n][i]*kb3[i*64+o] -----------------------
__global__ void k_hb(const float* __restrict__ h, const float* __restrict__ kb3,
                     float* __restrict__ hb) {
    __shared__ float t[4][64];
    int g = threadIdx.x >> 6, j = threadIdx.x & 63;
    int node = blockIdx.x * 4 + g;
    t[g][j] = h[node * 64 + j];
    __syncthreads();
    float acc = 0.f;
#pragma unroll
    for (int i = 0; i < 64; ++i) acc += t[g][i] * kb3[i * 64 + j];
    hb[node * 64 + j] = acc;
}

// ---- fused GEMM (k2 @ kW3P^T) + message dot + scatter-mean atomics ----------
// block: 128 edges x 128 cols (cols n' = o*64+i -> 2 complete o slices)
__global__ __launch_bounds__(256) void k_fused(const f16* __restrict__ A, const f16* __restrict__ B,
                                               const float* __restrict__ h, const float* __restrict__ hb,
                                               const int* __restrict__ ei, const float* __restrict__ dinv,
                                               float* __restrict__ agg) {
    __shared__ __align__(16) char smem[33280];   // GEMM: 2x16KB tiles; epilogue: hs[128][65] f32
    __shared__ int src_s[128];
    __shared__ int dst_s[128];
    __shared__ float dinv_s[128];
    char* lA = smem;
    char* lB = smem + 16384;
    int tid = threadIdx.x;
    int wave = tid >> 6, lane = tid & 63;
    int wr = wave >> 1, wc = wave & 1;
    int m0 = blockIdx.x * 128, n0 = blockIdx.y * 128;
    f32x4 acc[4][4] = {};
#pragma unroll 1
    for (int kt = 0; kt < 4; ++kt) {
        // stage A,B: 128 rows x 128 bytes each; 4 iters x 256 thr x 16B per tile
#pragma unroll
        for (int i = 0; i < 4; ++i) {
            int idx = i * 256 + tid;
            int r = idx >> 3, cb = (idx & 7) * 16;
            int cs = cb ^ ((r & 7) << 4);
            *(f16x8*)(lA + r * 128 + cs) = *(const f16x8*)(A + (size_t)(m0 + r) * 256 + kt * 64 + (cb >> 1));
            *(f16x8*)(lB + r * 128 + cs) = *(const f16x8*)(B + (size_t)(n0 + r) * 256 + kt * 64 + (cb >> 1));
        }
        __syncthreads();
#pragma unroll
        for (int kk = 0; kk < 2; ++kk) {
            int kb = kk * 64 + (lane >> 4) * 16;
            f16x8 af[4], bf[4];
#pragma unroll
            for (int m = 0; m < 4; ++m) {
                int r = wr * 64 + m * 16 + (lane & 15);
                af[m] = *(const f16x8*)(lA + r * 128 + (kb ^ ((r & 7) << 4)));
            }
#pragma unroll
            for (int n = 0; n < 4; ++n) {
                int r = wc * 64 + n * 16 + (lane & 15);
                bf[n] = *(const f16x8*)(lB + r * 128 + (kb ^ ((r & 7) << 4)));
            }
#pragma unroll
            for (int m = 0; m < 4; ++m)
#pragma unroll
                for (int n = 0; n < 4; ++n)
                    acc[m][n] = __builtin_amdgcn_mfma_f32_16x16x32_f16(af[m], bf[n], acc[m][n], 0, 0, 0);
        }
        __syncthreads();
    }
    // ---- epilogue: msg[e][o] = sum_i h_src[i]*(acc + bias) ; atomic into agg
    if (tid < 128) {
        int eg = m0 + tid;
        int s = 0, d = 0; float dv = 0.f;
        if (eg < N_EDGES) { s = ei[eg]; d = ei[N_EDGES + eg]; dv = dinv[d]; }
        src_s[tid] = s; dst_s[tid] = d; dinv_s[tid] = dv;
    }
    __syncthreads();
    float* hs = (float*)smem;   // [128][65]
#pragma unroll
    for (int i = 0; i < 32; ++i) {
        int idx = i * 256 + tid;
        int r = idx >> 6, c = idx & 63;
        hs[r * 65 + c] = h[src_s[r] * 64 + c];
    }
    __syncthreads();
    int o = (n0 >> 6) + wc;     // this wave's output channel
#pragma unroll
    for (int m = 0; m < 4; ++m) {
#pragma unroll
        for (int jj = 0; jj < 4; ++jj) {
            int el = wr * 64 + m * 16 + (lane >> 4) * 4 + jj;
            float v = 0.f;
#pragma unroll
            for (int n = 0; n < 4; ++n)
                v += acc[m][n][jj] * hs[el * 65 + n * 16 + (lane & 15)];
            v += __shfl_xor(v, 1); v += __shfl_xor(v, 2);
            v += __shfl_xor(v, 4); v += __shfl_xor(v, 8);
            if ((lane & 15) == 0) {
                int eg = m0 + el;
                if (eg < N_EDGES) {
                    float total = (v + hb[src_s[el] * 64 + o]) * dinv_s[el];
                    atomicAdd(&agg[dst_s[el] * 64 + o], total);
                }
            }
        }
    }
}

// ---------------- node update: h' = relu(agg + h@root + bias) ----------------
__global__ void k_update(const float* __restrict__ agg, const float* __restrict__ h,
                         const float* __restrict__ root, const float* __restrict__ bias,
                         float* __restrict__ hn) {
    __shared__ float t[4][64];
    int g = threadIdx.x >> 6, j = threadIdx.x & 63;
    int node = blockIdx.x * 4 + g;
    t[g][j] = h[node * 64 + j];
    __syncthreads();
    float acc = agg[node * 64 + j] + bias[j];
#pragma unroll
    for (int i = 0; i < 64; ++i) acc += t[g][i] * root[i * 64 + j];
    hn[node * 64 + j] = fmaxf(acc, 0.f);
}

// ---------------- output head ------------------------------------------------
__global__ void k_out(const float* __restrict__ h, const float* __restrict__ oW,
                      const float* __restrict__ ob, float* __restrict__ out) {
    int wg = (blockIdx.x * 256 + threadIdx.x) >> 6;
    int lane = threadIdx.x & 63;
    if (wg >= N_NODES) return;
    float p = h[wg * 64 + lane] * oW[lane];
#pragma unroll
    for (int s = 32; s > 0; s >>= 1) p += __shfl_xor(p, s);
    if (lane == 0) out[wg] = p + ob[0];
}

__global__ void k_sentinel(float* out) { out[0] = 1e30f; }

extern "C" void kernel_launch(void* const* d_in, const int* in_sizes, int n_in,
                              void* d_out, int out_size, void* d_ws, size_t ws_size,
                              hipStream_t stream) {
    const float* x          = (const float*)d_in[0];
    const float* edge_attr  = (const float*)d_in[1];
    const float* conditions = (const float*)d_in[2];
    const float* scale      = (const float*)d_in[3];
    const int*   edge_index = (const int*)d_in[4];
    const int*   batch      = (const int*)d_in[5];
    const float* nW1 = (const float*)d_in[6];  const float* nb1 = (const float*)d_in[7];
    const float* nW2 = (const float*)d_in[8];  const float* nb2 = (const float*)d_in[9];
    const float* cW1 = (const float*)d_in[10]; const float* cb1 = (const float*)d_in[11];
    const float* cW2 = (const float*)d_in[12]; const float* cb2 = (const float*)d_in[13];
    const float* kW1 = (const float*)d_in[14]; const float* kb1 = (const float*)d_in[15];
    const float* kW2 = (const float*)d_in[16]; const float* kb2 = (const float*)d_in[17];
    const float* kW3 = (const float*)d_in[18]; const float* kb3 = (const float*)d_in[19];
    const float* root = (const float*)d_in[20]; const float* conv_bias = (const float*)d_in[21];
    const float* oW  = (const float*)d_in[22]; const float* ob  = (const float*)d_in[23];
    float* out = (float*)d_out;

    char* ws = (char*)d_ws;
    size_t off = 0;
    auto alloc = [&](size_t bytes) -> char* {
        char* p = ws + off;
        off += (bytes + 255) & ~(size_t)255;
        return p;
    };
    float* h_a  = (float*)alloc((size_t)N_NODES * 64 * 4);
    float* h_b  = (float*)alloc((size_t)N_NODES * 64 * 4);
    float* agg  = (float*)alloc((size_t)N_NODES * 64 * 4);
    float* hb   = (float*)alloc((size_t)N_NODES * 64 * 4);
    float* u    = (float*)alloc(256 * 4);
    float* deg  = (float*)alloc((size_t)N_NODES * 4);
    f16*   k2   = (f16*)alloc((size_t)EPAD * 256 * 2);
    f16*   kW3P = (f16*)alloc((size_t)4096 * 256 * 2);
    // total ~43.2 MB

    if (off > ws_size) {  // workspace too small: distinct sentinel
        k_sentinel<<<1, 1, 0, stream>>>(out);
        return;
    }

    hipMemsetAsync(deg, 0, (size_t)N_NODES * 4, stream);
    k_node_enc<<<2500, 256, 0, stream>>>(x, nW1, nb1, nW2, nb2, h_a);
    k_cond_enc<<<1, 256, 0, stream>>>(conditions, scale, cW1, cb1, cW2, cb2, u, out + N_NODES);
    k_deg<<<(N_EDGES + 255) / 256, 256, 0, stream>>>(edge_index + N_EDGES, deg);
    k_deg_inv<<<(N_NODES + 255) / 256, 256, 0, stream>>>(deg);
    k_permute<<<64, 256, 0, stream>>>(kW3, kW3P);
    k_edge12<<<EPAD / 16, 256, 0, stream>>>(edge_attr, edge_index, batch, u, kW1, kb1, kW2, kb2, k2);

    float* hc = h_a; float* hn = h_b;
    for (int l = 0; l < 3; ++l) {
        hipMemsetAsync(agg, 0, (size_t)N_NODES * 64 * 4, stream);
        k_hb<<<2500, 256, 0, stream>>>(hc, kb3, hb);
        k_fused<<<dim3(EPAD / 128, 32), 256, 0, stream>>>(k2, kW3P, hc, hb, edge_index, deg, agg);
        k_update<<<2500, 256, 0, stream>>>(agg, hc, root, conv_bias, hn);
        float* tmp = hc; hc = hn; hn = tmp;
    }
    k_out<<<2500, 256, 0, stream>>>(hc, oW, ob, out);
}

// Round 3
// 1006.667 us; speedup vs baseline: 1.5980x; 1.5980x over previous
//
#include <hip/hip_runtime.h>
#include <hip/hip_fp16.h>

#define N_NODES 10000
#define N_EDGES 60000
#define EPAD    60032   // multiple of 128

typedef _Float16 f16;
typedef f16 f16x8 __attribute__((ext_vector_type(8)));
typedef float f32x4 __attribute__((ext_vector_type(4)));

// ---------------- node encoder: h = relu(x@nW1+nb1)@nW2+nb2 ----------------
__global__ void k_node_enc(const float* __restrict__ x, const float* __restrict__ W1,
                           const float* __restrict__ b1, const float* __restrict__ W2,
                           const float* __restrict__ b2, float* __restrict__ h) {
    __shared__ float t[4][64];
    int g = threadIdx.x >> 6, j = threadIdx.x & 63;
    int node = blockIdx.x * 4 + g;
    float acc = b1[j];
#pragma unroll
    for (int i = 0; i < 6; ++i) acc += x[node * 6 + i] * W1[i * 64 + j];
    t[g][j] = fmaxf(acc, 0.f);
    __syncthreads();
    float acc2 = b2[j];
#pragma unroll
    for (int i = 0; i < 64; ++i) acc2 += t[g][i] * W2[i * 64 + j];
    h[node * 64 + j] = acc2;
}

// ---------------- condition encoder -----------------------------------------
__global__ void k_cond_enc(const float* __restrict__ cond, const float* __restrict__ scl,
                           const float* __restrict__ W1, const float* __restrict__ b1,
                           const float* __restrict__ W2, const float* __restrict__ b2,
                           float* __restrict__ u, float* __restrict__ out_u) {
    __shared__ float t[4][64];
    __shared__ float cat[4][14];
    int g = threadIdx.x >> 6, j = threadIdx.x & 63;
    if (threadIdx.x < 56) {
        int b = threadIdx.x / 14, i = threadIdx.x % 14;
        cat[b][i] = (i < 10) ? cond[b * 10 + i] : scl[b * 4 + (i - 10)];
    }
    __syncthreads();
    float acc = b1[j];
#pragma unroll
    for (int i = 0; i < 14; ++i) acc += cat[g][i] * W1[i * 64 + j];
    t[g][j] = fmaxf(acc, 0.f);
    __syncthreads();
    float acc2 = b2[j];
#pragma unroll
    for (int i = 0; i < 64; ++i) acc2 += t[g][i] * W2[i * 64 + j];
    u[g * 64 + j] = acc2;
    out_u[g * 64 + j] = acc2;
}

// ---------------- degree -----------------------------------------------------
__global__ void k_deg(const int* __restrict__ dst, float* __restrict__ deg) {
    int e = blockIdx.x * 256 + threadIdx.x;
    if (e < N_EDGES) atomicAdd(&deg[dst[e]], 1.0f);
}
__global__ void k_deg_inv(float* __restrict__ deg) {
    int n = blockIdx.x * 256 + threadIdx.x;
    if (n < N_NODES) deg[n] = 1.0f / fmaxf(deg[n], 1.0f);
}

// ------- permute kW3: kW3P[o*64+i][k] = kW3[k][i*64+o], fp16; kb3P f32 -------
__global__ void k_permute(const float* __restrict__ kW3, const float* __restrict__ kb3,
                          f16* __restrict__ kW3P, float* __restrict__ kb3P) {
    __shared__ float T[256][65];
    int i = blockIdx.x;                 // 0..63
    int o = threadIdx.x & 63, kq = threadIdx.x >> 6;
    for (int kk = 0; kk < 64; ++kk) {
        int k = kk * 4 + kq;
        T[k][o] = kW3[(size_t)k * 4096 + i * 64 + o];
    }
    if (threadIdx.x < 64) kb3P[threadIdx.x * 64 + i] = kb3[i * 64 + threadIdx.x];
    __syncthreads();
    int ow = threadIdx.x >> 2, kc = (threadIdx.x & 3) * 64;
    f16* dstp = kW3P + (size_t)(ow * 64 + i) * 256 + kc;
    for (int c = 0; c < 8; ++c) {
        f16x8 v;
#pragma unroll
        for (int jj = 0; jj < 8; ++jj) v[jj] = (f16)T[kc + c * 8 + jj][ow];
        *(f16x8*)(dstp + c * 8) = v;
    }
}

// ---------------- fused edge MLP (k1 in LDS, k2 fp16 out) --------------------
__global__ __launch_bounds__(256) void k_edge12(const float* __restrict__ ea, const int* __restrict__ ei,
                                                const int* __restrict__ batch, const float* __restrict__ u,
                                                const float* __restrict__ W1, const float* __restrict__ b1,
                                                const float* __restrict__ W2, const float* __restrict__ b2,
                                                f16* __restrict__ k2) {
    __shared__ float u_s[256];
    __shared__ float ea_s[16][6];
    __shared__ int b_s[16];
    __shared__ float k1_s[16][128];
    int tid = threadIdx.x;
    int e0 = blockIdx.x * 16;
    u_s[tid] = u[tid];
    if (tid < 96) {
        int e = tid / 6, i = tid % 6;
        int eg = e0 + e;
        ea_s[e][i] = (eg < N_EDGES) ? ea[(size_t)eg * 6 + i] : 0.f;
    }
    if (tid < 16) {
        int eg = e0 + tid;
        b_s[tid] = (eg < N_EDGES) ? batch[ei[eg]] : 0;
    }
    __syncthreads();
    int j = tid & 127;
#pragma unroll 1
    for (int p = 0; p < 8; ++p) {
        int e = p * 2 + (tid >> 7);
        float acc = b1[j];
#pragma unroll
        for (int i = 0; i < 6; ++i) acc += ea_s[e][i] * W1[i * 128 + j];
        const float* ur = u_s + b_s[e] * 64;
#pragma unroll
        for (int i = 0; i < 64; ++i) acc += ur[i] * W1[(6 + i) * 128 + j];
        k1_s[e][j] = fmaxf(acc, 0.f);
    }
    __syncthreads();
    float acc2[16];
#pragma unroll
    for (int e = 0; e < 16; ++e) acc2[e] = b2[tid];
    for (int i = 0; i < 128; ++i) {
        float w = W2[(size_t)i * 256 + tid];
#pragma unroll
        for (int e = 0; e < 16; ++e) acc2[e] += k1_s[e][i] * w;
    }
#pragma unroll
    for (int e = 0; e < 16; ++e) {
        int eg = e0 + e;
        k2[(size_t)eg * 256 + tid] = (f16)((eg < N_EDGES) ? fmaxf(acc2[e], 0.f) : 0.f);
    }
}

// ---- fused GEMM + message dot + scatter-mean ---------------------------------
// block = 128 edges (A in registers), internal loop over 64 col-tiles (BN=64,
// one output channel o per tile). B tile staged in LDS (XOR-swizzled), bias
// folded into acc init, h*dinv held in registers.
__global__ __launch_bounds__(256) void k_fused(const f16* __restrict__ A, const f16* __restrict__ Bm,
                                               const float* __restrict__ kb3P, const float* __restrict__ h,
                                               const int* __restrict__ ei, const float* __restrict__ dinv,
                                               float* __restrict__ agg) {
    __shared__ __align__(16) char lB[32768];     // 64 rows x 512B, swizzled
    __shared__ int src_s[128];
    __shared__ int dst_s[128];
    __shared__ float dinv_s[128];
    int tid = threadIdx.x, wave = tid >> 6, lane = tid & 63;
    int m0 = blockIdx.x * 128;
    if (tid < 128) {
        int eg = m0 + tid; int s = 0, d = 0; float dv = 0.f;
        if (eg < N_EDGES) { s = ei[eg]; d = ei[N_EDGES + eg]; dv = dinv[d]; }
        src_s[tid] = s; dst_s[tid] = d; dinv_s[tid] = dv;
    }
    __syncthreads();
    // A fragments into registers: rows wave*32 + mf*16 + (lane&15), all K=256
    f16x8 a[2][8];
#pragma unroll
    for (int mf = 0; mf < 2; ++mf) {
        const f16* ap = A + (size_t)(m0 + wave * 32 + mf * 16 + (lane & 15)) * 256 + (lane >> 4) * 8;
#pragma unroll
        for (int ks = 0; ks < 8; ++ks) a[mf][ks] = *(const f16x8*)(ap + ks * 32);
    }
    // h rows (pre-scaled by dinv) into registers
    float hsr[2][4][4];
#pragma unroll
    for (int mf = 0; mf < 2; ++mf)
#pragma unroll
        for (int jj = 0; jj < 4; ++jj) {
            int el = wave * 32 + mf * 16 + (lane >> 4) * 4 + jj;
            const float* hp = h + (size_t)src_s[el] * 64 + (lane & 15);
            float dv = dinv_s[el];
#pragma unroll
            for (int nf = 0; nf < 4; ++nf) hsr[mf][jj][nf] = hp[nf * 16] * dv;
        }
    int swz = (lane & 7) << 4;
    int rbase = (lane & 15) * 512;
    int koff = (lane >> 4) * 16;
#pragma unroll 1
    for (int ct = 0; ct < 64; ++ct) {
        // stage B tile: issue global loads first (overlap with barrier)
        f16x8 st[8];
        const f16* bp = Bm + (size_t)ct * 64 * 256;
#pragma unroll
        for (int q = 0; q < 8; ++q) {
            int idx = q * 4096 + tid * 16;
            int r = idx >> 9, cb = idx & 511;
            st[q] = *(const f16x8*)(bp + r * 256 + (cb >> 1));
        }
        __syncthreads();   // previous tile's LDS reads done
#pragma unroll
        for (int q = 0; q < 8; ++q) {
            int idx = q * 4096 + tid * 16;
            int r = idx >> 9, cb = idx & 511;
            *(f16x8*)(lB + r * 512 + (cb ^ ((r & 7) << 4))) = st[q];
        }
        __syncthreads();
        // acc init = permuted bias (column-constant across rows)
        f32x4 acc[2][4];
#pragma unroll
        for (int nf = 0; nf < 4; ++nf) {
            float bv = kb3P[ct * 64 + nf * 16 + (lane & 15)];
            acc[0][nf] = {bv, bv, bv, bv};
            acc[1][nf] = {bv, bv, bv, bv};
        }
#pragma unroll
        for (int ks = 0; ks < 8; ++ks) {
            f16x8 bf[4];
#pragma unroll
            for (int nf = 0; nf < 4; ++nf)
                bf[nf] = *(const f16x8*)(lB + rbase + nf * 8192 + ((ks * 64 + koff) ^ swz));
#pragma unroll
            for (int mf = 0; mf < 2; ++mf)
#pragma unroll
                for (int nf = 0; nf < 4; ++nf)
                    acc[mf][nf] = __builtin_amdgcn_mfma_f32_16x16x32_f16(a[mf][ks], bf[nf], acc[mf][nf], 0, 0, 0);
        }
        // epilogue: msg[e][ct] = sum_i acc*hsr ; 16-lane reduce ; atomic
#pragma unroll
        for (int mf = 0; mf < 2; ++mf)
#pragma unroll
            for (int jj = 0; jj < 4; ++jj) {
                float v = acc[mf][0][jj] * hsr[mf][jj][0] + acc[mf][1][jj] * hsr[mf][jj][1]
                        + acc[mf][2][jj] * hsr[mf][jj][2] + acc[mf][3][jj] * hsr[mf][jj][3];
                v += __shfl_xor(v, 1); v += __shfl_xor(v, 2);
                v += __shfl_xor(v, 4); v += __shfl_xor(v, 8);
                int el = wave * 32 + mf * 16 + (lane >> 4) * 4 + jj;
                if ((lane & 15) == 0 && (m0 + el) < N_EDGES)
                    atomicAdd(&agg[(size_t)dst_s[el] * 64 + ct], v);
            }
    }
}

// ---------------- node update: h' = relu(agg + h@root + bias) ----------------
__global__ void k_update(const float* __restrict__ agg, const float* __restrict__ h,
                         const float* __restrict__ root, const float* __restrict__ bias,
                         float* __restrict__ hn) {
    __shared__ float t[4][64];
    int g = threadIdx.x >> 6, j = threadIdx.x & 63;
    int node = blockIdx.x * 4 + g;
    t[g][j] = h[node * 64 + j];
    __syncthreads();
    float acc = agg[node * 64 + j] + bias[j];
#pragma unroll
    for (int i = 0; i < 64; ++i) acc += t[g][i] * root[i * 64 + j];
    hn[node * 64 + j] = fmaxf(acc, 0.f);
}

// ---------------- output head ------------------------------------------------
__global__ void k_out(const float* __restrict__ h, const float* __restrict__ oW,
                      const float* __restrict__ ob, float* __restrict__ out) {
    int wg = (blockIdx.x * 256 + threadIdx.x) >> 6;
    int lane = threadIdx.x & 63;
    if (wg >= N_NODES) return;
    float p = h[wg * 64 + lane] * oW[lane];
#pragma unroll
    for (int s = 32; s > 0; s >>= 1) p += __shfl_xor(p, s);
    if (lane == 0) out[wg] = p + ob[0];
}

__global__ void k_sentinel(float* out) { out[0] = 1e30f; }

extern "C" void kernel_launch(void* const* d_in, const int* in_sizes, int n_in,
                              void* d_out, int out_size, void* d_ws, size_t ws_size,
                              hipStream_t stream) {
    const float* x          = (const float*)d_in[0];
    const float* edge_attr  = (const float*)d_in[1];
    const float* conditions = (const float*)d_in[2];
    const float* scale      = (const float*)d_in[3];
    const int*   edge_index = (const int*)d_in[4];
    const int*   batch      = (const int*)d_in[5];
    const float* nW1 = (const float*)d_in[6];  const float* nb1 = (const float*)d_in[7];
    const float* nW2 = (const float*)d_in[8];  const float* nb2 = (const float*)d_in[9];
    const float* cW1 = (const float*)d_in[10]; const float* cb1 = (const float*)d_in[11];
    const float* cW2 = (const float*)d_in[12]; const float* cb2 = (const float*)d_in[13];
    const float* kW1 = (const float*)d_in[14]; const float* kb1 = (const float*)d_in[15];
    const float* kW2 = (const float*)d_in[16]; const float* kb2 = (const float*)d_in[17];
    const float* kW3 = (const float*)d_in[18]; const float* kb3 = (const float*)d_in[19];
    const float* root = (const float*)d_in[20]; const float* conv_bias = (const float*)d_in[21];
    const float* oW  = (const float*)d_in[22]; const float* ob  = (const float*)d_in[23];
    float* out = (float*)d_out;

    char* ws = (char*)d_ws;
    size_t off = 0;
    auto alloc = [&](size_t bytes) -> char* {
        char* p = ws + off;
        off += (bytes + 255) & ~(size_t)255;
        return p;
    };
    float* h_a  = (float*)alloc((size_t)N_NODES * 64 * 4);
    float* h_b  = (float*)alloc((size_t)N_NODES * 64 * 4);
    float* agg  = (float*)alloc((size_t)N_NODES * 64 * 4);
    float* u    = (float*)alloc(256 * 4);
    float* deg  = (float*)alloc((size_t)N_NODES * 4);
    f16*   k2   = (f16*)alloc((size_t)EPAD * 256 * 2);
    f16*   kW3P = (f16*)alloc((size_t)4096 * 256 * 2);
    float* kb3P = (float*)alloc(4096 * 4);
    // total ~43 MB

    if (off > ws_size) {  // workspace too small: distinct sentinel
        k_sentinel<<<1, 1, 0, stream>>>(out);
        return;
    }

    hipMemsetAsync(deg, 0, (size_t)N_NODES * 4, stream);
    k_node_enc<<<2500, 256, 0, stream>>>(x, nW1, nb1, nW2, nb2, h_a);
    k_cond_enc<<<1, 256, 0, stream>>>(conditions, scale, cW1, cb1, cW2, cb2, u, out + N_NODES);
    k_deg<<<(N_EDGES + 255) / 256, 256, 0, stream>>>(edge_index + N_EDGES, deg);
    k_deg_inv<<<(N_NODES + 255) / 256, 256, 0, stream>>>(deg);
    k_permute<<<64, 256, 0, stream>>>(kW3, kb3, kW3P, kb3P);
    k_edge12<<<EPAD / 16, 256, 0, stream>>>(edge_attr, edge_index, batch, u, kW1, kb1, kW2, kb2, k2);

    float* hc = h_a; float* hn = h_b;
    for (int l = 0; l < 3; ++l) {
        hipMemsetAsync(agg, 0, (size_t)N_NODES * 64 * 4, stream);
        k_fused<<<dim3(EPAD / 128), 256, 0, stream>>>(k2, kW3P, kb3P, hc, edge_index, deg, agg);
        k_update<<<2500, 256, 0, stream>>>(agg, hc, root, conv_bias, hn);
        float* tmp = hc; hc = hn; hn = tmp;
    }
    k_out<<<2500, 256, 0, stream>>>(hc, oW, ob, out);
}

// Round 4
// 913.132 us; speedup vs baseline: 1.7617x; 1.1024x over previous
//
#include <hip/hip_runtime.h>
#include <hip/hip_fp16.h>

#define N_NODES 10000
#define N_EDGES 60000
#define EPAD    60032   // multiple of 128
#define CSPLIT  4
#define CT_PER  16      // 64 / CSPLIT

typedef _Float16 f16;
typedef f16 f16x8 __attribute__((ext_vector_type(8)));
typedef float f32x4 __attribute__((ext_vector_type(4)));

// ---------------- node encoder: h = relu(x@nW1+nb1)@nW2+nb2 ----------------
__global__ void k_node_enc(const float* __restrict__ x, const float* __restrict__ W1,
                           const float* __restrict__ b1, const float* __restrict__ W2,
                           const float* __restrict__ b2, float* __restrict__ h) {
    __shared__ float t[4][64];
    int g = threadIdx.x >> 6, j = threadIdx.x & 63;
    int node = blockIdx.x * 4 + g;
    float acc = b1[j];
#pragma unroll
    for (int i = 0; i < 6; ++i) acc += x[node * 6 + i] * W1[i * 64 + j];
    t[g][j] = fmaxf(acc, 0.f);
    __syncthreads();
    float acc2 = b2[j];
#pragma unroll
    for (int i = 0; i < 64; ++i) acc2 += t[g][i] * W2[i * 64 + j];
    h[node * 64 + j] = acc2;
}

// ---------------- condition encoder -----------------------------------------
__global__ void k_cond_enc(const float* __restrict__ cond, const float* __restrict__ scl,
                           const float* __restrict__ W1, const float* __restrict__ b1,
                           const float* __restrict__ W2, const float* __restrict__ b2,
                           float* __restrict__ u, float* __restrict__ out_u) {
    __shared__ float t[4][64];
    __shared__ float cat[4][14];
    int g = threadIdx.x >> 6, j = threadIdx.x & 63;
    if (threadIdx.x < 56) {
        int b = threadIdx.x / 14, i = threadIdx.x % 14;
        cat[b][i] = (i < 10) ? cond[b * 10 + i] : scl[b * 4 + (i - 10)];
    }
    __syncthreads();
    float acc = b1[j];
#pragma unroll
    for (int i = 0; i < 14; ++i) acc += cat[g][i] * W1[i * 64 + j];
    t[g][j] = fmaxf(acc, 0.f);
    __syncthreads();
    float acc2 = b2[j];
#pragma unroll
    for (int i = 0; i < 64; ++i) acc2 += t[g][i] * W2[i * 64 + j];
    u[g * 64 + j] = acc2;
    out_u[g * 64 + j] = acc2;
}

// ---------------- degree -----------------------------------------------------
__global__ void k_deg(const int* __restrict__ dst, float* __restrict__ deg) {
    int e = blockIdx.x * 256 + threadIdx.x;
    if (e < N_EDGES) atomicAdd(&deg[dst[e]], 1.0f);
}
__global__ void k_deg_inv(float* __restrict__ deg) {
    int n = blockIdx.x * 256 + threadIdx.x;
    if (n < N_NODES) deg[n] = 1.0f / fmaxf(deg[n], 1.0f);
}

// ------- permute kW3: kW3P[o*64+i][k] = kW3[k][i*64+o], fp16; kb3P f32 -------
__global__ void k_permute(const float* __restrict__ kW3, const float* __restrict__ kb3,
                          f16* __restrict__ kW3P, float* __restrict__ kb3P) {
    __shared__ float T[256][65];
    int i = blockIdx.x;                 // 0..63
    int o = threadIdx.x & 63, kq = threadIdx.x >> 6;
    for (int kk = 0; kk < 64; ++kk) {
        int k = kk * 4 + kq;
        T[k][o] = kW3[(size_t)k * 4096 + i * 64 + o];
    }
    if (threadIdx.x < 64) kb3P[threadIdx.x * 64 + i] = kb3[i * 64 + threadIdx.x];
    __syncthreads();
    int ow = threadIdx.x >> 2, kc = (threadIdx.x & 3) * 64;
    f16* dstp = kW3P + (size_t)(ow * 64 + i) * 256 + kc;
    for (int c = 0; c < 8; ++c) {
        f16x8 v;
#pragma unroll
        for (int jj = 0; jj < 8; ++jj) v[jj] = (f16)T[kc + c * 8 + jj][ow];
        *(f16x8*)(dstp + c * 8) = v;
    }
}

// ---------------- fused edge MLP (k1 in LDS, k2 fp16 out) --------------------
__global__ __launch_bounds__(256) void k_edge12(const float* __restrict__ ea, const int* __restrict__ ei,
                                                const int* __restrict__ batch, const float* __restrict__ u,
                                                const float* __restrict__ W1, const float* __restrict__ b1,
                                                const float* __restrict__ W2, const float* __restrict__ b2,
                                                f16* __restrict__ k2) {
    __shared__ float u_s[256];
    __shared__ float ea_s[16][6];
    __shared__ int b_s[16];
    __shared__ float k1_s[16][128];
    int tid = threadIdx.x;
    int e0 = blockIdx.x * 16;
    u_s[tid] = u[tid];
    if (tid < 96) {
        int e = tid / 6, i = tid % 6;
        int eg = e0 + e;
        ea_s[e][i] = (eg < N_EDGES) ? ea[(size_t)eg * 6 + i] : 0.f;
    }
    if (tid < 16) {
        int eg = e0 + tid;
        b_s[tid] = (eg < N_EDGES) ? batch[ei[eg]] : 0;
    }
    __syncthreads();
    int j = tid & 127;
#pragma unroll 1
    for (int p = 0; p < 8; ++p) {
        int e = p * 2 + (tid >> 7);
        float acc = b1[j];
#pragma unroll
        for (int i = 0; i < 6; ++i) acc += ea_s[e][i] * W1[i * 128 + j];
        const float* ur = u_s + b_s[e] * 64;
#pragma unroll
        for (int i = 0; i < 64; ++i) acc += ur[i] * W1[(6 + i) * 128 + j];
        k1_s[e][j] = fmaxf(acc, 0.f);
    }
    __syncthreads();
    float acc2[16];
#pragma unroll
    for (int e = 0; e < 16; ++e) acc2[e] = b2[tid];
    for (int i = 0; i < 128; ++i) {
        float w = W2[(size_t)i * 256 + tid];
#pragma unroll
        for (int e = 0; e < 16; ++e) acc2[e] += k1_s[e][i] * w;
    }
#pragma unroll
    for (int e = 0; e < 16; ++e) {
        int eg = e0 + e;
        k2[(size_t)eg * 256 + tid] = (f16)((eg < N_EDGES) ? fmaxf(acc2[e], 0.f) : 0.f);
    }
}

// ---- fused GEMM + message dot + scatter-mean ---------------------------------
// block = 128 edges x CT_PER col-tiles. A + h*dinv in registers. B tile in LDS
// with FRAGMENT-ORDERED layout: chunk (row r=nf*16+rl, ks, kg) stored at
// (nf*8+ks)*1024 + kg*256 + rl*16  -> wave fragment read = base + lane*16
// (linear, conflict-free); staging write chunk=q*256+tid (linear, conflict-free).
__global__ __launch_bounds__(256) void k_fused(const f16* __restrict__ A, const f16* __restrict__ Bm,
                                               const float* __restrict__ kb3P, const float* __restrict__ h,
                                               const int* __restrict__ ei, const float* __restrict__ dinv,
                                               float* __restrict__ agg) {
    __shared__ __align__(16) char lB[32768];
    __shared__ int src_s[128];
    __shared__ int dst_s[128];
    __shared__ float dinv_s[128];
    __shared__ float bias_s[CT_PER * 64];
    int tid = threadIdx.x, wave = tid >> 6, lane = tid & 63;
    int m0 = blockIdx.x * 128;
    int ct0 = blockIdx.y * CT_PER;
    if (tid < 128) {
        int eg = m0 + tid; int s = 0, d = 0; float dv = 0.f;
        if (eg < N_EDGES) { s = ei[eg]; d = ei[N_EDGES + eg]; dv = dinv[d]; }
        src_s[tid] = s; dst_s[tid] = d; dinv_s[tid] = dv;
    }
#pragma unroll
    for (int q = 0; q < CT_PER * 64 / 256; ++q)
        bias_s[q * 256 + tid] = kb3P[ct0 * 64 + q * 256 + tid];
    __syncthreads();
    // A fragments: rows wave*32 + mf*16 + (lane&15), k-chunks of 8 halves
    f16x8 a[2][8];
#pragma unroll
    for (int mf = 0; mf < 2; ++mf) {
        const f16* ap = A + (size_t)(m0 + wave * 32 + mf * 16 + (lane & 15)) * 256 + (lane >> 4) * 8;
#pragma unroll
        for (int ks = 0; ks < 8; ++ks) a[mf][ks] = *(const f16x8*)(ap + ks * 32);
    }
    // h rows (pre-scaled by dinv) into registers
    float hsr[2][4][4];
#pragma unroll
    for (int mf = 0; mf < 2; ++mf)
#pragma unroll
        for (int jj = 0; jj < 4; ++jj) {
            int el = wave * 32 + mf * 16 + (lane >> 4) * 4 + jj;
            const float* hp = h + (size_t)src_s[el] * 64 + (lane & 15);
            float dv = dinv_s[el];
#pragma unroll
            for (int nf = 0; nf < 4; ++nf) hsr[mf][jj][nf] = hp[nf * 16] * dv;
        }
    // prologue: prefetch first B tile into regs
    // chunk = q*256+tid: rl=tid&15, kg=(tid>>4)&3, v=q*4+wave, ks=v&7, nf=v>>3
    f16x8 st[8];
    {
        const f16* bp = Bm + (size_t)ct0 * 16384;
#pragma unroll
        for (int q = 0; q < 8; ++q) {
            int v = q * 4 + wave;
            st[q] = *(const f16x8*)(bp + (size_t)(((v >> 3) * 16) + (tid & 15)) * 256 + (v & 7) * 32 + ((tid >> 4) & 3) * 8);
        }
    }
#pragma unroll 1
    for (int ct = ct0; ct < ct0 + CT_PER; ++ct) {
        __syncthreads();           // previous tile's LDS reads done
#pragma unroll
        for (int q = 0; q < 8; ++q)
            *(f16x8*)(lB + (q * 256 + tid) * 16) = st[q];
        __syncthreads();
        if (ct + 1 < ct0 + CT_PER) {    // prefetch next tile (hides under MFMA)
            const f16* bp = Bm + (size_t)(ct + 1) * 16384;
#pragma unroll
            for (int q = 0; q < 8; ++q) {
                int v = q * 4 + wave;
                st[q] = *(const f16x8*)(bp + (size_t)(((v >> 3) * 16) + (tid & 15)) * 256 + (v & 7) * 32 + ((tid >> 4) & 3) * 8);
            }
        }
        // acc init = permuted bias (column-constant across rows)
        f32x4 acc[2][4];
#pragma unroll
        for (int nf = 0; nf < 4; ++nf) {
            float bv = bias_s[(ct - ct0) * 64 + nf * 16 + (lane & 15)];
            acc[0][nf] = {bv, bv, bv, bv};
            acc[1][nf] = {bv, bv, bv, bv};
        }
#pragma unroll
        for (int ks = 0; ks < 8; ++ks) {
            f16x8 bf[4];
#pragma unroll
            for (int nf = 0; nf < 4; ++nf)
                bf[nf] = *(const f16x8*)(lB + (nf * 8 + ks) * 1024 + lane * 16);
#pragma unroll
            for (int mf = 0; mf < 2; ++mf)
#pragma unroll
                for (int nf = 0; nf < 4; ++nf)
                    acc[mf][nf] = __builtin_amdgcn_mfma_f32_16x16x32_f16(a[mf][ks], bf[nf], acc[mf][nf], 0, 0, 0);
        }
        // epilogue: msg[e][ct] = sum_i acc*hsr ; 16-lane reduce ; atomic
#pragma unroll
        for (int mf = 0; mf < 2; ++mf)
#pragma unroll
            for (int jj = 0; jj < 4; ++jj) {
                float v = acc[mf][0][jj] * hsr[mf][jj][0] + acc[mf][1][jj] * hsr[mf][jj][1]
                        + acc[mf][2][jj] * hsr[mf][jj][2] + acc[mf][3][jj] * hsr[mf][jj][3];
                v += __shfl_xor(v, 1); v += __shfl_xor(v, 2);
                v += __shfl_xor(v, 4); v += __shfl_xor(v, 8);
                int el = wave * 32 + mf * 16 + (lane >> 4) * 4 + jj;
                if ((lane & 15) == 0 && (m0 + el) < N_EDGES)
                    atomicAdd(&agg[(size_t)dst_s[el] * 64 + ct], v);
            }
    }
}

// ---------------- node update: h' = relu(agg + h@root + bias) ----------------
__global__ void k_update(const float* __restrict__ agg, const float* __restrict__ h,
                         const float* __restrict__ root, const float* __restrict__ bias,
                         float* __restrict__ hn) {
    __shared__ float t[4][64];
    int g = threadIdx.x >> 6, j = threadIdx.x & 63;
    int node = blockIdx.x * 4 + g;
    t[g][j] = h[node * 64 + j];
    __syncthreads();
    float acc = agg[node * 64 + j] + bias[j];
#pragma unroll
    for (int i = 0; i < 64; ++i) acc += t[g][i] * root[i * 64 + j];
    hn[node * 64 + j] = fmaxf(acc, 0.f);
}

// ---------------- output head ------------------------------------------------
__global__ void k_out(const float* __restrict__ h, const float* __restrict__ oW,
                      const float* __restrict__ ob, float* __restrict__ out) {
    int wg = (blockIdx.x * 256 + threadIdx.x) >> 6;
    int lane = threadIdx.x & 63;
    if (wg >= N_NODES) return;
    float p = h[wg * 64 + lane] * oW[lane];
#pragma unroll
    for (int s = 32; s > 0; s >>= 1) p += __shfl_xor(p, s);
    if (lane == 0) out[wg] = p + ob[0];
}

__global__ void k_sentinel(float* out) { out[0] = 1e30f; }

extern "C" void kernel_launch(void* const* d_in, const int* in_sizes, int n_in,
                              void* d_out, int out_size, void* d_ws, size_t ws_size,
                              hipStream_t stream) {
    const float* x          = (const float*)d_in[0];
    const float* edge_attr  = (const float*)d_in[1];
    const float* conditions = (const float*)d_in[2];
    const float* scale      = (const float*)d_in[3];
    const int*   edge_index = (const int*)d_in[4];
    const int*   batch      = (const int*)d_in[5];
    const float* nW1 = (const float*)d_in[6];  const float* nb1 = (const float*)d_in[7];
    const float* nW2 = (const float*)d_in[8];  const float* nb2 = (const float*)d_in[9];
    const float* cW1 = (const float*)d_in[10]; const float* cb1 = (const float*)d_in[11];
    const float* cW2 = (const float*)d_in[12]; const float* cb2 = (const float*)d_in[13];
    const float* kW1 = (const float*)d_in[14]; const float* kb1 = (const float*)d_in[15];
    const float* kW2 = (const float*)d_in[16]; const float* kb2 = (const float*)d_in[17];
    const float* kW3 = (const float*)d_in[18]; const float* kb3 = (const float*)d_in[19];
    const float* root = (const float*)d_in[20]; const float* conv_bias = (const float*)d_in[21];
    const float* oW  = (const float*)d_in[22]; const float* ob  = (const float*)d_in[23];
    float* out = (float*)d_out;

    char* ws = (char*)d_ws;
    size_t off = 0;
    auto alloc = [&](size_t bytes) -> char* {
        char* p = ws + off;
        off += (bytes + 255) & ~(size_t)255;
        return p;
    };
    float* h_a  = (float*)alloc((size_t)N_NODES * 64 * 4);
    float* h_b  = (float*)alloc((size_t)N_NODES * 64 * 4);
    float* agg  = (float*)alloc((size_t)N_NODES * 64 * 4);
    float* u    = (float*)alloc(256 * 4);
    float* deg  = (float*)alloc((size_t)N_NODES * 4);
    f16*   k2   = (f16*)alloc((size_t)EPAD * 256 * 2);
    f16*   kW3P = (f16*)alloc((size_t)4096 * 256 * 2);
    float* kb3P = (float*)alloc(4096 * 4);
    // total ~43 MB

    if (off > ws_size) {  // workspace too small: distinct sentinel
        k_sentinel<<<1, 1, 0, stream>>>(out);
        return;
    }

    hipMemsetAsync(deg, 0, (size_t)N_NODES * 4, stream);
    k_node_enc<<<2500, 256, 0, stream>>>(x, nW1, nb1, nW2, nb2, h_a);
    k_cond_enc<<<1, 256, 0, stream>>>(conditions, scale, cW1, cb1, cW2, cb2, u, out + N_NODES);
    k_deg<<<(N_EDGES + 255) / 256, 256, 0, stream>>>(edge_index + N_EDGES, deg);
    k_deg_inv<<<(N_NODES + 255) / 256, 256, 0, stream>>>(deg);
    k_permute<<<64, 256, 0, stream>>>(kW3, kb3, kW3P, kb3P);
    k_edge12<<<EPAD / 16, 256, 0, stream>>>(edge_attr, edge_index, batch, u, kW1, kb1, kW2, kb2, k2);

    float* hc = h_a; float* hn = h_b;
    for (int l = 0; l < 3; ++l) {
        hipMemsetAsync(agg, 0, (size_t)N_NODES * 64 * 4, stream);
        k_fused<<<dim3(EPAD / 128, CSPLIT), 256, 0, stream>>>(k2, kW3P, kb3P, hc, edge_index, deg, agg);
        k_update<<<2500, 256, 0, stream>>>(agg, hc, root, conv_bias, hn);
        float* tmp = hc; hc = hn; hn = tmp;
    }
    k_out<<<2500, 256, 0, stream>>>(hc, oW, ob, out);
}

// Round 5
// 896.924 us; speedup vs baseline: 1.7935x; 1.0181x over previous
//
#include <hip/hip_runtime.h>
#include <hip/hip_fp16.h>

#define N_NODES 10000
#define N_EDGES 60000
#define EPAD    60032   // multiple of 128
#define CSPLIT  2
#define CT_PER  32      // 64 / CSPLIT

typedef _Float16 f16;
typedef f16 f16x8 __attribute__((ext_vector_type(8)));
typedef float f32x4 __attribute__((ext_vector_type(4)));

__device__ __forceinline__ void gload16(const void* g, void* l) {
    __builtin_amdgcn_global_load_lds((const __attribute__((address_space(1))) unsigned int*)g,
                                     (__attribute__((address_space(3))) unsigned int*)l, 16, 0, 0);
}

// combine a,b over xor-mask m: lanes with (lane&m)==0 end with a-pair-sum, else b-pair-sum
__device__ __forceinline__ float foldp(float a, float b, int m, int lane) {
    float x = (lane & m) ? b : a;
    float y = (lane & m) ? a : b;
    return x + __shfl_xor(y, m);
}

// ---------------- node encoder: h = relu(x@nW1+nb1)@nW2+nb2 ----------------
__global__ void k_node_enc(const float* __restrict__ x, const float* __restrict__ W1,
                           const float* __restrict__ b1, const float* __restrict__ W2,
                           const float* __restrict__ b2, float* __restrict__ h) {
    __shared__ float t[4][64];
    int g = threadIdx.x >> 6, j = threadIdx.x & 63;
    int node = blockIdx.x * 4 + g;
    float acc = b1[j];
#pragma unroll
    for (int i = 0; i < 6; ++i) acc += x[node * 6 + i] * W1[i * 64 + j];
    t[g][j] = fmaxf(acc, 0.f);
    __syncthreads();
    float acc2 = b2[j];
#pragma unroll
    for (int i = 0; i < 64; ++i) acc2 += t[g][i] * W2[i * 64 + j];
    h[node * 64 + j] = acc2;
}

// ---------------- condition encoder -----------------------------------------
__global__ void k_cond_enc(const float* __restrict__ cond, const float* __restrict__ scl,
                           const float* __restrict__ W1, const float* __restrict__ b1,
                           const float* __restrict__ W2, const float* __restrict__ b2,
                           float* __restrict__ u, float* __restrict__ out_u) {
    __shared__ float t[4][64];
    __shared__ float cat[4][14];
    int g = threadIdx.x >> 6, j = threadIdx.x & 63;
    if (threadIdx.x < 56) {
        int b = threadIdx.x / 14, i = threadIdx.x % 14;
        cat[b][i] = (i < 10) ? cond[b * 10 + i] : scl[b * 4 + (i - 10)];
    }
    __syncthreads();
    float acc = b1[j];
#pragma unroll
    for (int i = 0; i < 14; ++i) acc += cat[g][i] * W1[i * 64 + j];
    t[g][j] = fmaxf(acc, 0.f);
    __syncthreads();
    float acc2 = b2[j];
#pragma unroll
    for (int i = 0; i < 64; ++i) acc2 += t[g][i] * W2[i * 64 + j];
    u[g * 64 + j] = acc2;
    out_u[g * 64 + j] = acc2;
}

// ---------------- degree -----------------------------------------------------
__global__ void k_deg(const int* __restrict__ dst, float* __restrict__ deg) {
    int e = blockIdx.x * 256 + threadIdx.x;
    if (e < N_EDGES) atomicAdd(&deg[dst[e]], 1.0f);
}
__global__ void k_deg_inv(float* __restrict__ deg) {
    int n = blockIdx.x * 256 + threadIdx.x;
    if (n < N_NODES) deg[n] = 1.0f / fmaxf(deg[n], 1.0f);
}

// ------- permute kW3 into FRAGMENT-ORDERED tiles + kb3P ----------------------
// per ct (0..63): 32KB tile; chunk c = (nf*8+ks)*64 + kg*16 + rl holds 8 halves
// = rowmajor[(ct*64 + nf*16 + rl)][ks*32 + kg*8 .. +8]  (row n' = o*64+i, o=ct)
__global__ void k_permute(const float* __restrict__ kW3, const float* __restrict__ kb3,
                          f16* __restrict__ kW3P, float* __restrict__ kb3P) {
    __shared__ float T[256][65];
    int i = blockIdx.x;                 // 0..63 (inner input index)
    int o = threadIdx.x & 63, kq = threadIdx.x >> 6;
    for (int kk = 0; kk < 64; ++kk) {
        int k = kk * 4 + kq;
        T[k][o] = kW3[(size_t)k * 4096 + i * 64 + o];
    }
    if (threadIdx.x < 64) kb3P[threadIdx.x * 64 + i] = kb3[i * 64 + threadIdx.x];
    __syncthreads();
    int ow = threadIdx.x >> 2, kc = (threadIdx.x & 3) * 64;
    int nf = i >> 4, rl = i & 15;
    for (int c = 0; c < 8; ++c) {
        int k0 = kc + c * 8;
        int ks = k0 >> 5, kg = (k0 >> 3) & 3;
        int chunk = (nf * 8 + ks) * 64 + kg * 16 + rl;
        f16x8 v;
#pragma unroll
        for (int jj = 0; jj < 8; ++jj) v[jj] = (f16)T[k0 + jj][ow];
        *(f16x8*)(kW3P + (size_t)ow * 16384 + chunk * 8) = v;
    }
}

// ---------------- fused edge MLP (k1 in LDS, k2 fp16 out) --------------------
__global__ __launch_bounds__(256) void k_edge12(const float* __restrict__ ea, const int* __restrict__ ei,
                                                const int* __restrict__ batch, const float* __restrict__ u,
                                                const float* __restrict__ W1, const float* __restrict__ b1,
                                                const float* __restrict__ W2, const float* __restrict__ b2,
                                                f16* __restrict__ k2) {
    __shared__ float u_s[256];
    __shared__ float ea_s[16][6];
    __shared__ int b_s[16];
    __shared__ float k1_s[16][128];
    int tid = threadIdx.x;
    int e0 = blockIdx.x * 16;
    u_s[tid] = u[tid];
    if (tid < 96) {
        int e = tid / 6, i = tid % 6;
        int eg = e0 + e;
        ea_s[e][i] = (eg < N_EDGES) ? ea[(size_t)eg * 6 + i] : 0.f;
    }
    if (tid < 16) {
        int eg = e0 + tid;
        b_s[tid] = (eg < N_EDGES) ? batch[ei[eg]] : 0;
    }
    __syncthreads();
    int j = tid & 127;
#pragma unroll 1
    for (int p = 0; p < 8; ++p) {
        int e = p * 2 + (tid >> 7);
        float acc = b1[j];
#pragma unroll
        for (int i = 0; i < 6; ++i) acc += ea_s[e][i] * W1[i * 128 + j];
        const float* ur = u_s + b_s[e] * 64;
#pragma unroll
        for (int i = 0; i < 64; ++i) acc += ur[i] * W1[(6 + i) * 128 + j];
        k1_s[e][j] = fmaxf(acc, 0.f);
    }
    __syncthreads();
    float acc2[16];
#pragma unroll
    for (int e = 0; e < 16; ++e) acc2[e] = b2[tid];
    for (int i = 0; i < 128; ++i) {
        float w = W2[(size_t)i * 256 + tid];
#pragma unroll
        for (int e = 0; e < 16; ++e) acc2[e] += k1_s[e][i] * w;
    }
#pragma unroll
    for (int e = 0; e < 16; ++e) {
        int eg = e0 + e;
        k2[(size_t)eg * 256 + tid] = (f16)((eg < N_EDGES) ? fmaxf(acc2[e], 0.f) : 0.f);
    }
}

// ---- fused GEMM + message dot + scatter-mean --------------------------------
// block = 128 edges x CT_PER col-tiles; A + h*dinv in regs; B double-buffered
// via global_load_lds (fragment-ordered global); fold-reduce epilogue with
// 4-ct deferred atomics.
__global__ __launch_bounds__(256) void k_fused(const f16* __restrict__ A, const f16* __restrict__ Bf,
                                               const float* __restrict__ kb3P, const float* __restrict__ h,
                                               const int* __restrict__ ei, const float* __restrict__ dinv,
                                               float* __restrict__ agg) {
    __shared__ __align__(16) f16 lB[2][16384];       // 2 x 32KB
    __shared__ float bias_s[CT_PER * 64];            // 8KB
    __shared__ int src_s[128];
    __shared__ int dst_s[128];
    __shared__ float dinv_s[128];
    int tid = threadIdx.x, wave = tid >> 6, lane = tid & 63;
    int m0 = blockIdx.x * 128;
    int ct0 = blockIdx.y * CT_PER;
    if (tid < 128) {
        int eg = m0 + tid; int s = 0, d = 0; float dv = 0.f;
        if (eg < N_EDGES) { s = ei[eg]; d = ei[N_EDGES + eg]; dv = dinv[d]; }
        src_s[tid] = s; dst_s[tid] = d; dinv_s[tid] = dv;
    }
#pragma unroll
    for (int q = 0; q < CT_PER * 64 / 256; ++q)
        bias_s[q * 256 + tid] = kb3P[ct0 * 64 + q * 256 + tid];
    // issue first B tile (async global->LDS)
    {
        const f16* bp = Bf + (size_t)ct0 * 16384;
#pragma unroll
        for (int q = 0; q < 8; ++q)
            gload16(bp + (q * 256 + tid) * 8, &lB[0][(q * 256 + wave * 64) * 8]);
    }
    __syncthreads();   // src_s ready + first tile drained
    // A fragments: rows wave*32 + mf*16 + (lane&15), k-chunk (lane>>4)*8 + ks*32
    f16x8 a[2][8];
#pragma unroll
    for (int mf = 0; mf < 2; ++mf) {
        const f16* ap = A + (size_t)(m0 + wave * 32 + mf * 16 + (lane & 15)) * 256 + (lane >> 4) * 8;
#pragma unroll
        for (int ks = 0; ks < 8; ++ks) a[mf][ks] = *(const f16x8*)(ap + ks * 32);
    }
    // h rows (pre-scaled by dinv) in regs
    float hsr[2][4][4];
#pragma unroll
    for (int mf = 0; mf < 2; ++mf)
#pragma unroll
        for (int jj = 0; jj < 4; ++jj) {
            int el = wave * 32 + mf * 16 + (lane >> 4) * 4 + jj;
            const float* hp = h + (size_t)src_s[el] * 64 + (lane & 15);
            float dv = dinv_s[el];
#pragma unroll
            for (int nf = 0; nf < 4; ++nf) hsr[mf][jj][nf] = hp[nf * 16] * dv;
        }
    int cur = 0;
    float w4[4];
#pragma unroll 1
    for (int cto = 0; cto < CT_PER; cto += 4) {
#pragma unroll
        for (int q4 = 0; q4 < 4; ++q4) {
            int ctl = cto + q4;
            // issue next tile into alternate buffer (lands during this compute)
            if (ctl + 1 < CT_PER) {
                const f16* bp = Bf + (size_t)(ct0 + ctl + 1) * 16384;
#pragma unroll
                for (int q = 0; q < 8; ++q)
                    gload16(bp + (q * 256 + tid) * 8, &lB[cur ^ 1][(q * 256 + wave * 64) * 8]);
            }
            // acc init = bias (column-constant)
            f32x4 acc[2][4];
#pragma unroll
            for (int nf = 0; nf < 4; ++nf) {
                float bv = bias_s[ctl * 64 + nf * 16 + (lane & 15)];
                acc[0][nf] = {bv, bv, bv, bv};
                acc[1][nf] = {bv, bv, bv, bv};
            }
            const f16* lb = lB[cur];
#pragma unroll
            for (int ks = 0; ks < 8; ++ks) {
                f16x8 bf[4];
#pragma unroll
                for (int nf = 0; nf < 4; ++nf)
                    bf[nf] = *(const f16x8*)(lb + (nf * 8 + ks) * 512 + lane * 8);
#pragma unroll
                for (int mf = 0; mf < 2; ++mf)
#pragma unroll
                    for (int nf = 0; nf < 4; ++nf)
                        acc[mf][nf] = __builtin_amdgcn_mfma_f32_16x16x32_f16(a[mf][ks], bf[nf], acc[mf][nf], 0, 0, 0);
            }
            // per-lane partials then fold-reduce (8 shfl total)
            float v[8];
#pragma unroll
            for (int mf = 0; mf < 2; ++mf)
#pragma unroll
                for (int jj = 0; jj < 4; ++jj)
                    v[mf * 4 + jj] = acc[mf][0][jj] * hsr[mf][jj][0] + acc[mf][1][jj] * hsr[mf][jj][1]
                                   + acc[mf][2][jj] * hsr[mf][jj][2] + acc[mf][3][jj] * hsr[mf][jj][3];
            float t0 = foldp(v[0], v[1], 1, lane);
            float t1 = foldp(v[2], v[3], 1, lane);
            float t2 = foldp(v[4], v[5], 1, lane);
            float t3 = foldp(v[6], v[7], 1, lane);
            float u0 = foldp(t0, t1, 2, lane);
            float u1 = foldp(t2, t3, 2, lane);
            float s0 = foldp(u0, u1, 4, lane);
            s0 += __shfl_xor(s0, 8);
            // lane holds full i-sum for value j = lane&7 (mf=(lane>>2)&1, jj=lane&3),
            // edge el = wave*32 + mf*16 + (lane>>4)*4 + jj ; duplicate at lane&8
            w4[q4] = s0;
            if (q4 == 3) {   // flush 4 cts (pad edges have dinv=0 -> add 0.0)
                if (!(lane & 8)) {
                    int mf = (lane >> 2) & 1, jj = lane & 3;
                    int el = wave * 32 + mf * 16 + (lane >> 4) * 4 + jj;
                    float* ap2 = agg + (size_t)dst_s[el] * 64 + ct0 + cto;
                    atomicAdd(ap2 + 0, w4[0]);
                    atomicAdd(ap2 + 1, w4[1]);
                    atomicAdd(ap2 + 2, w4[2]);
                    atomicAdd(ap2 + 3, w4[3]);
                }
            }
            cur ^= 1;
            __syncthreads();   // single barrier: RAW for next tile, WAR for this one
        }
    }
}

// ---------------- node update: h' = relu(agg + h@root + bias) ----------------
__global__ void k_update(const float* __restrict__ agg, const float* __restrict__ h,
                         const float* __restrict__ root, const float* __restrict__ bias,
                         float* __restrict__ hn) {
    __shared__ float t[4][64];
    int g = threadIdx.x >> 6, j = threadIdx.x & 63;
    int node = blockIdx.x * 4 + g;
    t[g][j] = h[node * 64 + j];
    __syncthreads();
    float acc = agg[node * 64 + j] + bias[j];
#pragma unroll
    for (int i = 0; i < 64; ++i) acc += t[g][i] * root[i * 64 + j];
    hn[node * 64 + j] = fmaxf(acc, 0.f);
}

// ---------------- output head ------------------------------------------------
__global__ void k_out(const float* __restrict__ h, const float* __restrict__ oW,
                      const float* __restrict__ ob, float* __restrict__ out) {
    int wg = (blockIdx.x * 256 + threadIdx.x) >> 6;
    int lane = threadIdx.x & 63;
    if (wg >= N_NODES) return;
    float p = h[wg * 64 + lane] * oW[lane];
#pragma unroll
    for (int s = 32; s > 0; s >>= 1) p += __shfl_xor(p, s);
    if (lane == 0) out[wg] = p + ob[0];
}

__global__ void k_sentinel(float* out) { out[0] = 1e30f; }

extern "C" void kernel_launch(void* const* d_in, const int* in_sizes, int n_in,
                              void* d_out, int out_size, void* d_ws, size_t ws_size,
                              hipStream_t stream) {
    const float* x          = (const float*)d_in[0];
    const float* edge_attr  = (const float*)d_in[1];
    const float* conditions = (const float*)d_in[2];
    const float* scale      = (const float*)d_in[3];
    const int*   edge_index = (const int*)d_in[4];
    const int*   batch      = (const int*)d_in[5];
    const float* nW1 = (const float*)d_in[6];  const float* nb1 = (const float*)d_in[7];
    const float* nW2 = (const float*)d_in[8];  const float* nb2 = (const float*)d_in[9];
    const float* cW1 = (const float*)d_in[10]; const float* cb1 = (const float*)d_in[11];
    const float* cW2 = (const float*)d_in[12]; const float* cb2 = (const float*)d_in[13];
    const float* kW1 = (const float*)d_in[14]; const float* kb1 = (const float*)d_in[15];
    const float* kW2 = (const float*)d_in[16]; const float* kb2 = (const float*)d_in[17];
    const float* kW3 = (const float*)d_in[18]; const float* kb3 = (const float*)d_in[19];
    const float* root = (const float*)d_in[20]; const float* conv_bias = (const float*)d_in[21];
    const float* oW  = (const float*)d_in[22]; const float* ob  = (const float*)d_in[23];
    float* out = (float*)d_out;

    char* ws = (char*)d_ws;
    size_t off = 0;
    auto alloc = [&](size_t bytes) -> char* {
        char* p = ws + off;
        off += (bytes + 255) & ~(size_t)255;
        return p;
    };
    float* h_a  = (float*)alloc((size_t)N_NODES * 64 * 4);
    float* h_b  = (float*)alloc((size_t)N_NODES * 64 * 4);
    float* agg  = (float*)alloc((size_t)N_NODES * 64 * 4);
    float* u    = (float*)alloc(256 * 4);
    float* deg  = (float*)alloc((size_t)N_NODES * 4);
    f16*   k2   = (f16*)alloc((size_t)EPAD * 256 * 2);
    f16*   kW3P = (f16*)alloc((size_t)4096 * 256 * 2);
    float* kb3P = (float*)alloc(4096 * 4);
    // total ~43 MB

    if (off > ws_size) {  // workspace too small: distinct sentinel
        k_sentinel<<<1, 1, 0, stream>>>(out);
        return;
    }

    hipMemsetAsync(deg, 0, (size_t)N_NODES * 4, stream);
    k_node_enc<<<2500, 256, 0, stream>>>(x, nW1, nb1, nW2, nb2, h_a);
    k_cond_enc<<<1, 256, 0, stream>>>(conditions, scale, cW1, cb1, cW2, cb2, u, out + N_NODES);
    k_deg<<<(N_EDGES + 255) / 256, 256, 0, stream>>>(edge_index + N_EDGES, deg);
    k_deg_inv<<<(N_NODES + 255) / 256, 256, 0, stream>>>(deg);
    k_permute<<<64, 256, 0, stream>>>(kW3, kb3, kW3P, kb3P);
    k_edge12<<<EPAD / 16, 256, 0, stream>>>(edge_attr, edge_index, batch, u, kW1, kb1, kW2, kb2, k2);

    float* hc = h_a; float* hn = h_b;
    for (int l = 0; l < 3; ++l) {
        hipMemsetAsync(agg, 0, (size_t)N_NODES * 64 * 4, stream);
        k_fused<<<dim3(EPAD / 128, CSPLIT), 256, 0, stream>>>(k2, kW3P, kb3P, hc, edge_index, deg, agg);
        k_update<<<2500, 256, 0, stream>>>(agg, hc, root, conv_bias, hn);
        float* tmp = hc; hc = hn; hn = tmp;
    }
    k_out<<<2500, 256, 0, stream>>>(hc, oW, ob, out);
}